// Round 16
// baseline (284.053 us; speedup 1.0000x reference)
//
#include <hip/hip_runtime.h>
#include <hip/hip_bf16.h>
#include <hip/hip_fp16.h>
#include <stdint.h>

typedef short s16x8 __attribute__((ext_vector_type(8)));
typedef unsigned short u16x8 __attribute__((ext_vector_type(8)));
typedef _Float16 f16x8 __attribute__((ext_vector_type(8)));
typedef __fp16 h16x2 __attribute__((ext_vector_type(2)));   // builtin's return type
typedef float f32x4 __attribute__((ext_vector_type(4)));

__device__ __forceinline__ unsigned short f2h(float f) {
    __half h = __float2half(f);
    union { __half h; unsigned short u; } c; c.h = h; return c.u;
}
// pack two f32 -> two f16 in one VALU op (v_cvt_pkrtz_f16_f32; RTZ, <=1ulp)
__device__ __forceinline__ unsigned pkh(float a, float b) {
    union { h16x2 h; unsigned u; } c;
    c.h = __builtin_amdgcn_cvt_pkrtz(a, b);
    return c.u;
}
// packed PReLU on 8 fp16 lanes: max(v,0) + a*min(v,0)  (v_pk_max/min/fma)
__device__ __forceinline__ f16x8 prelu8(f16x8 v, f16x8 a) {
    f16x8 z = {};
    f16x8 pos = __builtin_elementwise_max(v, z);
    f16x8 neg = __builtin_elementwise_min(v, z);
    return pos + a * neg;
}

// ---------------------------------------------------------------------------
// K1 (R15, unchanged): conv1 fp16 MFMA + fused weight repack (blocks >= 2048).
// Bias in MFMA acc-init; PReLU deferred to pool (packed fp16).
// -> p1 fp16 [n][23][23][32], post-PReLU.
// ---------------------------------------------------------------------------
__global__ __launch_bounds__(256, 6)
void k1_conv1(const float* __restrict__ x, const float* __restrict__ c1w,
              const float* __restrict__ c1b, const float* __restrict__ a1,
              unsigned short* __restrict__ p1,
              const float* __restrict__ c2w, const float* __restrict__ c3w,
              const float* __restrict__ c4w, const float* __restrict__ d5w,
              unsigned short* __restrict__ w2, unsigned short* __restrict__ w3,
              unsigned short* __restrict__ w4, unsigned short* __restrict__ w5) {
    const int n = blockIdx.x, tid = threadIdx.x;

    if (n >= 2048) {            // ---- repack path (old k0), 74 blocks ----
        for (int t0 = (n - 2048) * 256 + tid; t0 < 382976; t0 += 18944) {
            int t = t0;
            if (t < 18432) {    // w2 [9][64][32] <- c2w [64][32][3][3]
                int kpos = t / 2048, rem = t % 2048, oc = rem / 32, ic = rem % 32;
                w2[t] = f2h(c2w[(oc * 32 + ic) * 9 + kpos]);
                continue;
            }
            t -= 18432;
            if (t < 36864) {    // w3 [9][64][64] <- c3w [64][64][3][3]
                int kpos = t / 4096, rem = t % 4096, oc = rem / 64, ic = rem % 64;
                w3[t] = f2h(c3w[(oc * 64 + ic) * 9 + kpos]);
                continue;
            }
            t -= 36864;
            if (t < 32768) {    // w4 [4][128][64] <- c4w [128][64][2][2]
                int kpos = t / 8192, rem = t % 8192, oc = rem / 64, ic = rem % 64;
                w4[t] = f2h(c4w[(oc * 64 + ic) * 4 + kpos]);
                continue;
            }
            t -= 32768;
            w5[t] = f2h(d5w[t]);    // [256][1152] fp16
        }
        return;
    }

    __shared__ unsigned short xstrip[1008];      // [ic][7 rows][48] fp16 (2 KB)
    __shared__ unsigned short cbuf[230 * 40];    // [flat px][32 oc + 8 pad] fp16 (18.4 KB)
    __shared__ unsigned short wlds[1024];        // [32 oc][32 k] fp16, k>=27 zero (2 KB)
    __shared__ unsigned short a1h[32];           // alpha fp16 packed source
    __shared__ float bls[32];

    const int w = tid >> 6, lane = tid & 63, q = lane >> 4, l16 = lane & 15;

    for (int t = tid; t < 1024; t += 256) {
        int oc = t >> 5, k = t & 31;
        wlds[t] = (k < 27) ? f2h(c1w[oc * 27 + k]) : (unsigned short)0;
    }
    if (tid < 32) { bls[tid] = c1b[tid]; a1h[tid] = f2h(a1[tid]); }
    __syncthreads();

    f16x8 Wf[2];
    #pragma unroll
    for (int nt = 0; nt < 2; ++nt) {
        union { u16x8 u; f16x8 f; } cc;
        cc.u = *(const u16x8*)(wlds + (nt * 16 + l16) * 32 + q * 8);
        Wf[nt] = cc.f;
    }

    // bias for acc-init: C row = oc = nt*16 + q*4 + r
    f32x4 binit[2];
    #pragma unroll
    for (int nt = 0; nt < 2; ++nt)
    #pragma unroll
    for (int r = 0; r < 4; ++r) binit[nt][r] = bls[nt * 16 + q * 4 + r];

    int off[8];
    #pragma unroll
    for (int j = 0; j < 8; ++j) {
        int k = q * 8 + j;
        int kk = k < 27 ? k : 26;
        int ic = kk / 9, r9 = kk - ic * 9, ky = r9 / 3, kx = r9 - ky * 3;
        off[j] = ic * 336 + ky * 48 + kx;
    }

    auto do_pool = [&](int sp, int nprows, int kymax) {
        int ntask = nprows * 92;
        int t = tid;
        if (t < ntask) {
            int ocg = t & 3; unsigned r2 = (unsigned)t >> 2;
            int px = (int)(r2 % 23u), py_l = (int)(r2 / 23u);
            int kxmax = (px == 22) ? 2 : 3;
            int base = (2 * py_l * 46 + 2 * px) * 40 + ocg * 8;
            f16x8 mx;
            #pragma unroll
            for (int j = 0; j < 8; ++j) mx[j] = (_Float16)(-60000.f);
            #pragma unroll
            for (int ky = 0; ky < 3; ++ky) {
                if (ky < kymax) {
                    #pragma unroll
                    for (int kx = 0; kx < 3; ++kx) {
                        if (kx < kxmax) {
                            union { uint4 u; f16x8 f; } d;
                            d.u = *(const uint4*)&cbuf[base + (ky * 46 + kx) * 40];
                            mx = __builtin_elementwise_max(mx, d.f);
                        }
                    }
                }
            }
            union { uint4 u; f16x8 f; } aal;
            aal.u = *(const uint4*)&a1h[ocg * 8];
            union { f16x8 f; uint4 u; } o; o.f = prelu8(mx, aal.f);
            int py = 2 * sp + py_l;
            *(uint4*)&p1[n * 16928 + (py * 23 + px) * 32 + ocg * 8] = o.u;
        }
    };

    for (int s = 0; s < 12; ++s) {
        const int nrows = (s == 11) ? 2 : 5;
        const int P = 46 * nrows;
        const int ntiles = (P + 15) >> 4;
        const int xr0 = 4 * s;

        {
            int t4 = tid;
            if (t4 < 252) {
                int ic = t4 / 84;
                int rem4 = t4 * 4 - ic * 336;
                int rr = rem4 / 48, col = rem4 - rr * 48;
                int row = xr0 + rr; if (row > 47) row = 47;
                float4 f = *(const float4*)(x + n * 6912 + ic * 2304 + row * 48 + col);
                uint2 o; o.x = pkh(f.x, f.y); o.y = pkh(f.z, f.w);
                *(uint2*)&xstrip[t4 * 4] = o;
            }
        }
        if (s > 0) do_pool(s - 1, 2, 3);
        __syncthreads();

        for (int T = w; T < ntiles; T += 4) {
            int px = T * 16 + l16;
            int p = px < P ? px : P - 1;
            int ry = p / 46, cx = p - ry * 46;
            int basex = ry * 48 + cx;
            union { u16x8 u; f16x8 f; } xcc;
            #pragma unroll
            for (int j = 0; j < 8; ++j) xcc.u[j] = xstrip[basex + off[j]];
            f16x8 Xf = xcc.f;
            f32x4 acc[2] = {binit[0], binit[1]};
            #pragma unroll
            for (int nt = 0; nt < 2; ++nt)
                acc[nt] = __builtin_amdgcn_mfma_f32_16x16x32_f16(Wf[nt], Xf, acc[nt], 0, 0, 0);
            if (px < P) {
                #pragma unroll
                for (int nt = 0; nt < 2; ++nt) {
                    uint2 pk; pk.x = pkh(acc[nt][0], acc[nt][1]);
                    pk.y = pkh(acc[nt][2], acc[nt][3]);
                    *(uint2*)&cbuf[px * 40 + nt * 16 + q * 4] = pk;
                }
            }
        }
        __syncthreads();
    }
    do_pool(11, 1, 2);
}

// ---------------------------------------------------------------------------
// K23 (R16): fused conv2+pool2+conv3+pool3+conv4, fp16.
// OCCUPANCY 4->5 blocks/CU: strips shrunk to 1 pool row (3 conv rows,
// 10 strips). LDS 28.5 KB (was 36.9):
//   xs  [115 px][32] @0      (7360)   <- p1 rows 2s..2s+4, linear copy
//   c2s [63][64]     @7360   (8064)
//   p2s [100][64]    @15424  (12800)
//   c3buf [64][64] @0, p3 [16][64] @8192 (alias dead xs/c2s)
// VGPR 64 -> fits 20 waves/CU. Cost: 24 barriers (was 14), p1 re-stage
// 2.17x (was 1.75x) — both second-order at 20 waves.
// ---------------------------------------------------------------------------
__global__ __launch_bounds__(256, 2)
void k23_fused(const unsigned short* __restrict__ p1, const unsigned short* __restrict__ w2,
               const float* __restrict__ c2b, const float* __restrict__ a2,
               const unsigned short* __restrict__ w3, const float* __restrict__ c3b,
               const float* __restrict__ a3, const unsigned short* __restrict__ w4,
               const float* __restrict__ c4b, const float* __restrict__ a4,
               unsigned short* __restrict__ flat) {
    __shared__ __align__(16) char smem[28224];
    __shared__ unsigned short a2h[64], a3h[64];
    unsigned short* xs    = (unsigned short*)(smem);            // [115 px][32]
    unsigned short* c2s   = (unsigned short*)(smem + 7360);     // [63][64]
    unsigned short* p2s   = (unsigned short*)(smem + 15424);    // [100][64]
    unsigned short* c3buf = (unsigned short*)(smem);            // alias (8 KB)
    unsigned short* p3    = (unsigned short*)(smem + 8192);     // alias [16][64]

    const int n = blockIdx.x, tid = threadIdx.x;
    const int w = tid >> 6, lane = tid & 63, q = lane >> 4, l16 = lane & 15;
    const unsigned short* p1n = p1 + n * 16928;

    const int npair = w & 1, tset = w >> 1;
    const int ocA = npair * 32 + l16, ocB = npair * 32 + 16 + l16;

    if (tid < 64) { a2h[tid] = f2h(a2[tid]); a3h[tid] = f2h(a3[tid]); }

    f16x8 B2[9][2];
    #pragma unroll
    for (int kp = 0; kp < 9; ++kp) {
        union { u16x8 u; f16x8 f; } c0, c1;
        c0.u = *(const u16x8*)(w2 + (kp * 64 + ocA) * 32 + q * 8);
        c1.u = *(const u16x8*)(w2 + (kp * 64 + ocB) * 32 + q * 8);
        B2[kp][0] = c0.f; B2[kp][1] = c1.f;
    }
    const float b2a = c2b[ocA], b2b = c2b[ocB];

    // stage p1 rows 2s..2s+4 into xs (linear uint4 copy: 460, offset 184s)
    auto stage = [&](int s) {
        const uint4* src = ((const uint4*)p1n) + 184 * s;
        for (int t = tid; t < 460; t += 256) ((uint4*)xs)[t] = src[t];
    };

    // conv2 strip: conv rows 2s..2s+2 (P=63 px) -> c2s local rows 0..62
    auto conv2_strip = [&]() {
        const int P = 63, ntiles = 4, half = 2;
        const int T0 = tset * half;
        const int T1 = T0 + half;
        for (int T = T0; T < T1; ++T) {
            int m = T * 16 + l16;
            int p = m < P ? m : P - 1;
            int ry = p / 21, ox = p - ry * 21;
            const unsigned short* ab = xs + (ry * 23 + ox) * 32 + q * 8;
            f32x4 acc0 = {b2a, b2a, b2a, b2a}, acc1 = {b2b, b2b, b2b, b2b};
            #pragma unroll
            for (int kp = 0; kp < 9; ++kp) {
                int ky = kp / 3, kx = kp - ky * 3;
                union { u16x8 u; f16x8 f; } av;
                av.u = *(const u16x8*)(ab + (ky * 23 + kx) * 32);
                acc0 = __builtin_amdgcn_mfma_f32_16x16x32_f16(av.f, B2[kp][0], acc0, 0, 0, 0);
                acc1 = __builtin_amdgcn_mfma_f32_16x16x32_f16(av.f, B2[kp][1], acc1, 0, 0, 0);
            }
            int rowb = T * 16 + q * 4;
            #pragma unroll
            for (int r = 0; r < 4; ++r) {
                int row = rowb + r;
                if (row < P) {
                    c2s[row * 64 + npair * 32 + l16]      = f2h(acc0[r]);
                    c2s[row * 64 + npair * 32 + 16 + l16] = f2h(acc1[r]);
                }
            }
        }
    };

    // pool2 strip s (pool row py=s): packed max + packed PReLU -> p2s
    auto pool_strip = [&](int s) {
        if (tid < 80) {
            int ocg = tid & 7, px = tid >> 3;
            int base = (2 * px) * 64 + ocg * 8;
            f16x8 mx;
            #pragma unroll
            for (int j = 0; j < 8; ++j) mx[j] = (_Float16)(-60000.f);
            #pragma unroll
            for (int ky = 0; ky < 3; ++ky)
            #pragma unroll
            for (int kx = 0; kx < 3; ++kx) {
                union { uint4 u; f16x8 f; } d;
                d.u = *(const uint4*)&c2s[base + (ky * 21 + kx) * 64];
                mx = __builtin_elementwise_max(mx, d.f);
            }
            union { uint4 u; f16x8 f; } aal;
            aal.u = *(const uint4*)&a2h[ocg * 8];
            union { f16x8 f; uint4 u; } o; o.f = prelu8(mx, aal.f);
            *(uint4*)&p2s[(s * 10 + px) * 64 + ocg * 8] = o.u;
        }
    };

    stage(0);
    __syncthreads();
    for (int s = 0; s < 10; ++s) {
        conv2_strip();
        __syncthreads();
        pool_strip(s);
        if (s < 9) stage(s + 1);
        __syncthreads();
    }

    // conv3: wave w owns oc-tile w x all 4 M-tiles; 18 chunks, B prefetched
    {
        const int oc3 = w * 16 + l16;
        int mbase[4];
        #pragma unroll
        for (int j = 0; j < 4; ++j) {
            int px = j * 16 + l16;
            int oy = px >> 3, ox = px & 7;
            mbase[j] = (oy * 10 + ox) * 64 + q * 8;
        }
        const float bias3 = c3b[oc3];
        f32x4 acc3[4];
        #pragma unroll
        for (int j = 0; j < 4; ++j) acc3[j] = f32x4{bias3, bias3, bias3, bias3};
        union { u16x8 u; f16x8 f; } bc;
        bc.u = *(const u16x8*)(w3 + oc3 * 64 + q * 8);
        f16x8 B3c = bc.f;
        for (int c = 0; c < 18; ++c) {
            f16x8 B3n = B3c;
            if (c < 17) {
                int cn = c + 1;
                union { u16x8 u; f16x8 f; } bn;
                bn.u = *(const u16x8*)(w3 + ((cn >> 1) * 64 + oc3) * 64 + (cn & 1) * 32 + q * 8);
                B3n = bn.f;
            }
            int kp = c >> 1, ky = kp / 3, kx = kp - ky * 3;
            int aoff = (ky * 10 + kx) * 64 + (c & 1) * 32;
            #pragma unroll
            for (int j = 0; j < 4; ++j) {
                union { u16x8 u; f16x8 f; } av;
                av.u = *(const u16x8*)(p2s + mbase[j] + aoff);
                acc3[j] = __builtin_amdgcn_mfma_f32_16x16x32_f16(av.f, B3c, acc3[j], 0, 0, 0);
            }
            B3c = B3n;
        }
        #pragma unroll
        for (int j = 0; j < 4; ++j)
        #pragma unroll
        for (int r = 0; r < 4; ++r) {
            int row = j * 16 + q * 4 + r;
            c3buf[row * 64 + oc3] = f2h(acc3[j][r]);   // pre-PReLU
        }
    }
    __syncthreads();

    // pool3 2x2 s2 (8->4), packed max + packed PReLU -> p3 [16][64]
    if (tid < 128) {
        int ocg = tid & 7, r = tid >> 3;   // r = output px 0..15
        int py = r >> 2, pxo = r & 3;
        f16x8 mx;
        #pragma unroll
        for (int j = 0; j < 8; ++j) mx[j] = (_Float16)(-60000.f);
        #pragma unroll
        for (int ky = 0; ky < 2; ++ky)
        #pragma unroll
        for (int kx = 0; kx < 2; ++kx) {
            union { uint4 u; f16x8 f; } d;
            d.u = *(const uint4*)&c3buf[((py * 2 + ky) * 8 + pxo * 2 + kx) * 64 + ocg * 8];
            mx = __builtin_elementwise_max(mx, d.f);
        }
        union { uint4 u; f16x8 f; } aal;
        aal.u = *(const uint4*)&a3h[ocg * 8];
        union { f16x8 f; uint4 u; } o; o.f = prelu8(mx, aal.f);
        *(uint4*)&p3[r * 64 + ocg * 8] = o.u;
    }
    __syncthreads();

    // conv4: wave w owns oc-tiles 2w,2w+1; 8 chunks; bias in init, scalar PReLU
    {
        int px = l16 < 9 ? l16 : 8;
        int oy = px / 3, ox = px - oy * 3;
        const int mb4 = (oy * 4 + ox) * 64 + q * 8;
        const int oc4a = (w * 2) * 16 + l16, oc4b = (w * 2 + 1) * 16 + l16;
        const float b4a = c4b[oc4a], b4b = c4b[oc4b];
        f32x4 acc4[2] = {{b4a, b4a, b4a, b4a}, {b4b, b4b, b4b, b4b}};
        f16x8 B4c[2];
        {
            union { u16x8 u; f16x8 f; } b0, b1;
            b0.u = *(const u16x8*)(w4 + oc4a * 64 + q * 8);
            b1.u = *(const u16x8*)(w4 + oc4b * 64 + q * 8);
            B4c[0] = b0.f; B4c[1] = b1.f;
        }
        for (int c = 0; c < 8; ++c) {
            f16x8 B4n[2] = {B4c[0], B4c[1]};
            if (c < 7) {
                int cn = c + 1;
                int boff = (cn >> 1) * 8192 + (cn & 1) * 32 + q * 8;
                union { u16x8 u; f16x8 f; } b0, b1;
                b0.u = *(const u16x8*)(w4 + boff + oc4a * 64);
                b1.u = *(const u16x8*)(w4 + boff + oc4b * 64);
                B4n[0] = b0.f; B4n[1] = b1.f;
            }
            int kp = c >> 1, ky = kp >> 1, kx = kp & 1;
            union { u16x8 u; f16x8 f; } av;
            av.u = *(const u16x8*)(p3 + mb4 + (ky * 4 + kx) * 64 + (c & 1) * 32);
            acc4[0] = __builtin_amdgcn_mfma_f32_16x16x32_f16(av.f, B4c[0], acc4[0], 0, 0, 0);
            acc4[1] = __builtin_amdgcn_mfma_f32_16x16x32_f16(av.f, B4c[1], acc4[1], 0, 0, 0);
            B4c[0] = B4n[0]; B4c[1] = B4n[1];
        }
        #pragma unroll
        for (int h = 0; h < 2; ++h) {
            int oc = h ? oc4b : oc4a;
            float al = a4[oc];
            #pragma unroll
            for (int r = 0; r < 4; ++r) {
                int row = q * 4 + r;
                if (row < 9) {
                    int hy = row / 3, wx = row - hy * 3;
                    float val = acc4[h][r];
                    val = fmaxf(val, 0.f) + al * fminf(val, 0.f);
                    flat[(unsigned)n * 1152u + (wx * 3 + hy) * 128 + oc] = f2h(val);
                }
            }
        }
    }
}

// ---------------------------------------------------------------------------
// K5 (R15, unchanged): merged d5 GEMM + heads; bias in acc-init.
// ---------------------------------------------------------------------------
__global__ __launch_bounds__(256, 2)
void k5_fused(const unsigned short* __restrict__ flat, const unsigned short* __restrict__ w5,
              const float* __restrict__ d5b, const float* __restrict__ a5,
              const float* __restrict__ d61w, const float* __restrict__ d61b,
              const float* __restrict__ d62w, const float* __restrict__ d62b,
              const float* __restrict__ d63w, const float* __restrict__ d63b,
              float* __restrict__ out) {
    __shared__ float hL[16 * 260];
    __shared__ float wl[16 * 260];
    __shared__ float lg[256];
    const int blk = blockIdx.x, tid = threadIdx.x;
    const int w = tid >> 6, lane = tid & 63, q = lane >> 4, l16 = lane & 15;
    const int img0 = blk * 16;
    const int img = img0 + l16;

    f32x4 acc[4];
    #pragma unroll
    for (int nt = 0; nt < 4; ++nt) {
        float b = d5b[w * 64 + nt * 16 + l16];
        acc[nt] = f32x4{b, b, b, b};
    }

    for (int c = 0; c < 36; ++c) {
        int k0 = c * 32 + q * 8;
        union { u16x8 u; f16x8 f; } av;
        av.u = *(const u16x8*)(flat + (unsigned)img * 1152u + k0);
        #pragma unroll
        for (int nt = 0; nt < 4; ++nt) {
            int oc = w * 64 + nt * 16 + l16;
            union { u16x8 u; f16x8 f; } bv;
            bv.u = *(const u16x8*)(w5 + (unsigned)oc * 1152u + k0);
            acc[nt] = __builtin_amdgcn_mfma_f32_16x16x32_f16(av.f, bv.f, acc[nt], 0, 0, 0);
        }
    }
    // epilogue: PReLU -> hL (fp32); C row=q*4+r=image, col=l16
    #pragma unroll
    for (int nt = 0; nt < 4; ++nt) {
        int oc = w * 64 + nt * 16 + l16;
        float al = a5[oc];
        #pragma unroll
        for (int r = 0; r < 4; ++r) {
            int im = q * 4 + r;
            float v = acc[nt][r];
            v = fmaxf(v, 0.f) + al * fminf(v, 0.f);
            hL[im * 260 + oc] = v;
        }
    }
    // stage 16 head weight rows (fp32)
    {
        int o = tid >> 4, seg = tid & 15;
        const float* wrow = (o < 2) ? d61w + o * 256
                          : (o < 6) ? d62w + (o - 2) * 256
                          :           d63w + (o - 6) * 256;
        #pragma unroll
        for (int j = 0; j < 4; ++j)
            *(float4*)&wl[o * 260 + seg * 16 + j * 4] = ((const float4*)wrow)[seg * 4 + j];
    }
    __syncthreads();

    const int im = tid >> 4, o = tid & 15;
    {
        float bias = (o < 2) ? d61b[o] : (o < 6) ? d62b[o - 2] : d63b[o - 6];
        float s = bias;
        const float4* ha = (const float4*)&hL[im * 260];
        const float4* wa = (const float4*)&wl[o * 260];
        #pragma unroll 8
        for (int k = 0; k < 64; ++k) {
            float4 a = ha[k], b = wa[k];
            s += a.x * b.x + a.y * b.y + a.z * b.z + a.w * b.w;
        }
        lg[im * 16 + o] = s;
    }
    __syncthreads();
    {
        int gimg = img0 + im;
        float v = lg[im * 16 + o];
        if (o >= 2 && o < 6) {
            out[gimg * 4 + (o - 2)] = v;                       // b [N,4]
        } else if (o >= 6) {
            out[8192 + gimg * 10 + (o - 6)] = v;               // c [N,10]
        } else {
            float l0 = lg[im * 16 + 0], l1 = lg[im * 16 + 1];
            float mx = fmaxf(l0, l1);
            float e0 = __expf(l0 - mx), e1 = __expf(l1 - mx);
            out[28672 + gimg * 2 + o] = (o == 0 ? e0 : e1) / (e0 + e1);   // a [N,2]
        }
    }
}

// ---------------------------------------------------------------------------
extern "C" void kernel_launch(void* const* d_in, const int* in_sizes, int n_in,
                              void* d_out, int out_size, void* d_ws, size_t ws_size,
                              hipStream_t stream) {
    (void)in_sizes; (void)n_in; (void)out_size; (void)ws_size;
    const float* x    = (const float*)d_in[0];
    const float* c1w  = (const float*)d_in[1];
    const float* c1b  = (const float*)d_in[2];
    const float* a1   = (const float*)d_in[3];
    const float* c2w  = (const float*)d_in[4];
    const float* c2b  = (const float*)d_in[5];
    const float* a2   = (const float*)d_in[6];
    const float* c3w  = (const float*)d_in[7];
    const float* c3b  = (const float*)d_in[8];
    const float* a3   = (const float*)d_in[9];
    const float* c4w  = (const float*)d_in[10];
    const float* c4b  = (const float*)d_in[11];
    const float* a4   = (const float*)d_in[12];
    const float* d5w  = (const float*)d_in[13];
    const float* d5b  = (const float*)d_in[14];
    const float* a5   = (const float*)d_in[15];
    const float* d61w = (const float*)d_in[16];
    const float* d61b = (const float*)d_in[17];
    const float* d62w = (const float*)d_in[18];
    const float* d62b = (const float*)d_in[19];
    const float* d63w = (const float*)d_in[20];
    const float* d63b = (const float*)d_in[21];

    char* ws = (char*)d_ws;
    // region plan:
    //   p1    @ 0          : 69,337,088 B  (live through k23_fused)
    //   flat  @ 69,337,088 : 4,718,592 B
    //   weights @ 186,777,600 : ~766 KB
    unsigned short* p1    = (unsigned short*)(ws + 0);
    unsigned short* flat  = (unsigned short*)(ws + 69337088);
    unsigned short* w2    = (unsigned short*)(ws + 186777600);
    unsigned short* w3    = (unsigned short*)(ws + 186814464);
    unsigned short* w4    = (unsigned short*)(ws + 186888192);
    unsigned short* w5    = (unsigned short*)(ws + 186953728);

    k1_conv1 <<<2122, 256, 0, stream>>>(x, c1w, c1b, a1, p1,
                                        c2w, c3w, c4w, d5w, w2, w3, w4, w5);
    k23_fused<<<2048, 256, 0, stream>>>(p1, w2, c2b, a2, w3, c3b, a3, w4, c4b, a4, flat);
    k5_fused <<<128, 256, 0, stream>>>(flat, w5, d5b, a5, d61w, d61b, d62w, d62b,
                                       d63w, d63b, (float*)d_out);
}

// Round 17
// 281.330 us; speedup vs baseline: 1.0097x; 1.0097x over previous
//
#include <hip/hip_runtime.h>
#include <hip/hip_bf16.h>
#include <hip/hip_fp16.h>
#include <stdint.h>

typedef short s16x8 __attribute__((ext_vector_type(8)));
typedef unsigned short u16x8 __attribute__((ext_vector_type(8)));
typedef _Float16 f16x8 __attribute__((ext_vector_type(8)));
typedef __fp16 h16x2 __attribute__((ext_vector_type(2)));   // builtin's return type
typedef float f32x4 __attribute__((ext_vector_type(4)));

__device__ __forceinline__ unsigned short f2h(float f) {
    __half h = __float2half(f);
    union { __half h; unsigned short u; } c; c.h = h; return c.u;
}
// pack two f32 -> two f16 in one VALU op (v_cvt_pkrtz_f16_f32; RTZ, <=1ulp)
__device__ __forceinline__ unsigned pkh(float a, float b) {
    union { h16x2 h; unsigned u; } c;
    c.h = __builtin_amdgcn_cvt_pkrtz(a, b);
    return c.u;
}
// packed PReLU on 8 fp16 lanes: max(v,0) + a*min(v,0)  (v_pk_max/min/fma)
__device__ __forceinline__ f16x8 prelu8(f16x8 v, f16x8 a) {
    f16x8 z = {};
    f16x8 pos = __builtin_elementwise_max(v, z);
    f16x8 neg = __builtin_elementwise_min(v, z);
    return pos + a * neg;
}

// ---------------------------------------------------------------------------
// K1 (R17): as R15 but __launch_bounds__(256,7) — LDS 22.5 KB fits 7
// blocks/CU; (256,6) was the binding occupancy cap. Fused weight repack
// (blocks >= 2048). Bias in MFMA acc-init; PReLU deferred to pool.
// -> p1 fp16 [n][23][23][32], post-PReLU.
// ---------------------------------------------------------------------------
__global__ __launch_bounds__(256, 7)
void k1_conv1(const float* __restrict__ x, const float* __restrict__ c1w,
              const float* __restrict__ c1b, const float* __restrict__ a1,
              unsigned short* __restrict__ p1,
              const float* __restrict__ c2w, const float* __restrict__ c3w,
              const float* __restrict__ c4w, const float* __restrict__ d5w,
              unsigned short* __restrict__ w2, unsigned short* __restrict__ w3,
              unsigned short* __restrict__ w4, unsigned short* __restrict__ w5) {
    const int n = blockIdx.x, tid = threadIdx.x;

    if (n >= 2048) {            // ---- repack path (old k0), 74 blocks ----
        for (int t0 = (n - 2048) * 256 + tid; t0 < 382976; t0 += 18944) {
            int t = t0;
            if (t < 18432) {    // w2 [9][64][32] <- c2w [64][32][3][3]
                int kpos = t / 2048, rem = t % 2048, oc = rem / 32, ic = rem % 32;
                w2[t] = f2h(c2w[(oc * 32 + ic) * 9 + kpos]);
                continue;
            }
            t -= 18432;
            if (t < 36864) {    // w3 [9][64][64] <- c3w [64][64][3][3]
                int kpos = t / 4096, rem = t % 4096, oc = rem / 64, ic = rem % 64;
                w3[t] = f2h(c3w[(oc * 64 + ic) * 9 + kpos]);
                continue;
            }
            t -= 36864;
            if (t < 32768) {    // w4 [4][128][64] <- c4w [128][64][2][2]
                int kpos = t / 8192, rem = t % 8192, oc = rem / 64, ic = rem % 64;
                w4[t] = f2h(c4w[(oc * 64 + ic) * 4 + kpos]);
                continue;
            }
            t -= 32768;
            w5[t] = f2h(d5w[t]);    // [256][1152] fp16
        }
        return;
    }

    __shared__ unsigned short xstrip[1008];      // [ic][7 rows][48] fp16 (2 KB)
    __shared__ unsigned short cbuf[230 * 40];    // [flat px][32 oc + 8 pad] fp16 (18.4 KB)
    __shared__ unsigned short wlds[1024];        // [32 oc][32 k] fp16, k>=27 zero (2 KB)
    __shared__ unsigned short a1h[32];           // alpha fp16 packed source
    __shared__ float bls[32];

    const int w = tid >> 6, lane = tid & 63, q = lane >> 4, l16 = lane & 15;

    for (int t = tid; t < 1024; t += 256) {
        int oc = t >> 5, k = t & 31;
        wlds[t] = (k < 27) ? f2h(c1w[oc * 27 + k]) : (unsigned short)0;
    }
    if (tid < 32) { bls[tid] = c1b[tid]; a1h[tid] = f2h(a1[tid]); }
    __syncthreads();

    f16x8 Wf[2];
    #pragma unroll
    for (int nt = 0; nt < 2; ++nt) {
        union { u16x8 u; f16x8 f; } cc;
        cc.u = *(const u16x8*)(wlds + (nt * 16 + l16) * 32 + q * 8);
        Wf[nt] = cc.f;
    }

    // bias for acc-init: C row = oc = nt*16 + q*4 + r
    f32x4 binit[2];
    #pragma unroll
    for (int nt = 0; nt < 2; ++nt)
    #pragma unroll
    for (int r = 0; r < 4; ++r) binit[nt][r] = bls[nt * 16 + q * 4 + r];

    int off[8];
    #pragma unroll
    for (int j = 0; j < 8; ++j) {
        int k = q * 8 + j;
        int kk = k < 27 ? k : 26;
        int ic = kk / 9, r9 = kk - ic * 9, ky = r9 / 3, kx = r9 - ky * 3;
        off[j] = ic * 336 + ky * 48 + kx;
    }

    auto do_pool = [&](int sp, int nprows, int kymax) {
        int ntask = nprows * 92;
        int t = tid;
        if (t < ntask) {
            int ocg = t & 3; unsigned r2 = (unsigned)t >> 2;
            int px = (int)(r2 % 23u), py_l = (int)(r2 / 23u);
            int kxmax = (px == 22) ? 2 : 3;
            int base = (2 * py_l * 46 + 2 * px) * 40 + ocg * 8;
            f16x8 mx;
            #pragma unroll
            for (int j = 0; j < 8; ++j) mx[j] = (_Float16)(-60000.f);
            #pragma unroll
            for (int ky = 0; ky < 3; ++ky) {
                if (ky < kymax) {
                    #pragma unroll
                    for (int kx = 0; kx < 3; ++kx) {
                        if (kx < kxmax) {
                            union { uint4 u; f16x8 f; } d;
                            d.u = *(const uint4*)&cbuf[base + (ky * 46 + kx) * 40];
                            mx = __builtin_elementwise_max(mx, d.f);
                        }
                    }
                }
            }
            union { uint4 u; f16x8 f; } aal;
            aal.u = *(const uint4*)&a1h[ocg * 8];
            union { f16x8 f; uint4 u; } o; o.f = prelu8(mx, aal.f);
            int py = 2 * sp + py_l;
            *(uint4*)&p1[n * 16928 + (py * 23 + px) * 32 + ocg * 8] = o.u;
        }
    };

    for (int s = 0; s < 12; ++s) {
        const int nrows = (s == 11) ? 2 : 5;
        const int P = 46 * nrows;
        const int ntiles = (P + 15) >> 4;
        const int xr0 = 4 * s;

        {
            int t4 = tid;
            if (t4 < 252) {
                int ic = t4 / 84;
                int rem4 = t4 * 4 - ic * 336;
                int rr = rem4 / 48, col = rem4 - rr * 48;
                int row = xr0 + rr; if (row > 47) row = 47;
                float4 f = *(const float4*)(x + n * 6912 + ic * 2304 + row * 48 + col);
                uint2 o; o.x = pkh(f.x, f.y); o.y = pkh(f.z, f.w);
                *(uint2*)&xstrip[t4 * 4] = o;
            }
        }
        if (s > 0) do_pool(s - 1, 2, 3);
        __syncthreads();

        for (int T = w; T < ntiles; T += 4) {
            int px = T * 16 + l16;
            int p = px < P ? px : P - 1;
            int ry = p / 46, cx = p - ry * 46;
            int basex = ry * 48 + cx;
            union { u16x8 u; f16x8 f; } xcc;
            #pragma unroll
            for (int j = 0; j < 8; ++j) xcc.u[j] = xstrip[basex + off[j]];
            f16x8 Xf = xcc.f;
            f32x4 acc[2] = {binit[0], binit[1]};
            #pragma unroll
            for (int nt = 0; nt < 2; ++nt)
                acc[nt] = __builtin_amdgcn_mfma_f32_16x16x32_f16(Wf[nt], Xf, acc[nt], 0, 0, 0);
            if (px < P) {
                #pragma unroll
                for (int nt = 0; nt < 2; ++nt) {
                    uint2 pk; pk.x = pkh(acc[nt][0], acc[nt][1]);
                    pk.y = pkh(acc[nt][2], acc[nt][3]);
                    *(uint2*)&cbuf[px * 40 + nt * 16 + q * 4] = pk;
                }
            }
        }
        __syncthreads();
    }
    do_pool(11, 1, 2);
}

// ---------------------------------------------------------------------------
// K23 (R17 = R15 revert): fused conv2+pool2+conv3+pool3+conv4, fp16,
// strip = 2 pool rows (5 strips, 14 barriers) — R16's strip=1 (24 barriers)
// regressed 91->96.5 us: occupancy did NOT rise (38.9 vs 39.6) and the finer
// phases just added barrier convergence. 4 blocks/CU, LDS 36.9 KB.
//   xs  [161 px][32] @0      (10304)  <- p1 rows 4s..4s+6, linear copy
//   c2s [105][64]    @10304  (13440)
//   p2s [100][64]    @23744  (12800)
//   c3buf [64][64] @0, p3 [16][64] @8192 (alias dead xs)
// ---------------------------------------------------------------------------
__global__ __launch_bounds__(256, 2)
void k23_fused(const unsigned short* __restrict__ p1, const unsigned short* __restrict__ w2,
               const float* __restrict__ c2b, const float* __restrict__ a2,
               const unsigned short* __restrict__ w3, const float* __restrict__ c3b,
               const float* __restrict__ a3, const unsigned short* __restrict__ w4,
               const float* __restrict__ c4b, const float* __restrict__ a4,
               unsigned short* __restrict__ flat) {
    __shared__ __align__(16) char smem[36544];
    __shared__ unsigned short a2h[64], a3h[64];
    unsigned short* xs    = (unsigned short*)(smem);            // [161 px][32]
    unsigned short* c2s   = (unsigned short*)(smem + 10304);    // [105][64]
    unsigned short* p2s   = (unsigned short*)(smem + 23744);    // [100][64]
    unsigned short* c3buf = (unsigned short*)(smem);            // alias (8 KB)
    unsigned short* p3    = (unsigned short*)(smem + 8192);     // alias [16][64]

    const int n = blockIdx.x, tid = threadIdx.x;
    const int w = tid >> 6, lane = tid & 63, q = lane >> 4, l16 = lane & 15;
    const unsigned short* p1n = p1 + n * 16928;

    const int npair = w & 1, tset = w >> 1;
    const int ocA = npair * 32 + l16, ocB = npair * 32 + 16 + l16;

    if (tid < 64) { a2h[tid] = f2h(a2[tid]); a3h[tid] = f2h(a3[tid]); }

    f16x8 B2[9][2];
    #pragma unroll
    for (int kp = 0; kp < 9; ++kp) {
        union { u16x8 u; f16x8 f; } c0, c1;
        c0.u = *(const u16x8*)(w2 + (kp * 64 + ocA) * 32 + q * 8);
        c1.u = *(const u16x8*)(w2 + (kp * 64 + ocB) * 32 + q * 8);
        B2[kp][0] = c0.f; B2[kp][1] = c1.f;
    }
    const float b2a = c2b[ocA], b2b = c2b[ocB];

    // stage p1 rows 4s..4s+6 into xs (pure linear uint4 copy, 644 per strip)
    auto stage = [&](int s) {
        const uint4* src = ((const uint4*)p1n) + 368 * s;
        for (int t = tid; t < 644; t += 256) ((uint4*)xs)[t] = src[t];
    };

    // conv2 strip: conv rows 4s..4s+4 (P=105 px) -> c2s (pre-PReLU, bias in)
    auto conv2_strip = [&]() {
        const int P = 105, ntiles = 7, half = 4;
        const int T0 = tset * half;
        const int T1 = (T0 + half) < ntiles ? (T0 + half) : ntiles;
        for (int T = T0; T < T1; ++T) {
            int m = T * 16 + l16;
            int p = m < P ? m : P - 1;
            int ry = p / 21, ox = p - ry * 21;
            const unsigned short* ab = xs + (ry * 23 + ox) * 32 + q * 8;
            f32x4 acc0 = {b2a, b2a, b2a, b2a}, acc1 = {b2b, b2b, b2b, b2b};
            #pragma unroll
            for (int kp = 0; kp < 9; ++kp) {
                int ky = kp / 3, kx = kp - ky * 3;
                union { u16x8 u; f16x8 f; } av;
                av.u = *(const u16x8*)(ab + (ky * 23 + kx) * 32);
                acc0 = __builtin_amdgcn_mfma_f32_16x16x32_f16(av.f, B2[kp][0], acc0, 0, 0, 0);
                acc1 = __builtin_amdgcn_mfma_f32_16x16x32_f16(av.f, B2[kp][1], acc1, 0, 0, 0);
            }
            int rowb = T * 16 + q * 4;
            #pragma unroll
            for (int r = 0; r < 4; ++r) {
                int row = rowb + r;
                if (row < P) {
                    c2s[row * 64 + npair * 32 + l16]      = f2h(acc0[r]);
                    c2s[row * 64 + npair * 32 + 16 + l16] = f2h(acc1[r]);
                }
            }
        }
    };

    // pool2 strip s: packed max + packed PReLU -> p2s (post-PReLU)
    auto pool_strip = [&](int s) {
        if (tid < 160) {
            int ocg = tid & 7; int r2 = tid >> 3;
            int px = r2 % 10, pyl = r2 / 10;
            int base = (2 * pyl * 21 + 2 * px) * 64 + ocg * 8;
            f16x8 mx;
            #pragma unroll
            for (int j = 0; j < 8; ++j) mx[j] = (_Float16)(-60000.f);
            #pragma unroll
            for (int ky = 0; ky < 3; ++ky)
            #pragma unroll
            for (int kx = 0; kx < 3; ++kx) {
                union { uint4 u; f16x8 f; } d;
                d.u = *(const uint4*)&c2s[base + (ky * 21 + kx) * 64];
                mx = __builtin_elementwise_max(mx, d.f);
            }
            union { uint4 u; f16x8 f; } aal;
            aal.u = *(const uint4*)&a2h[ocg * 8];
            union { f16x8 f; uint4 u; } o; o.f = prelu8(mx, aal.f);
            *(uint4*)&p2s[((2 * s + pyl) * 10 + px) * 64 + ocg * 8] = o.u;
        }
    };

    stage(0);
    __syncthreads();
    for (int s = 0; s < 5; ++s) {
        conv2_strip();
        __syncthreads();
        pool_strip(s);
        if (s < 4) stage(s + 1);
        __syncthreads();
    }

    // conv3: wave w owns oc-tile w x all 4 M-tiles; 18 chunks, B prefetched
    {
        const int oc3 = w * 16 + l16;
        int mbase[4];
        #pragma unroll
        for (int j = 0; j < 4; ++j) {
            int px = j * 16 + l16;
            int oy = px >> 3, ox = px & 7;
            mbase[j] = (oy * 10 + ox) * 64 + q * 8;
        }
        const float bias3 = c3b[oc3];
        f32x4 acc3[4];
        #pragma unroll
        for (int j = 0; j < 4; ++j) acc3[j] = f32x4{bias3, bias3, bias3, bias3};
        union { u16x8 u; f16x8 f; } bc;
        bc.u = *(const u16x8*)(w3 + oc3 * 64 + q * 8);
        f16x8 B3c = bc.f;
        for (int c = 0; c < 18; ++c) {
            f16x8 B3n = B3c;
            if (c < 17) {
                int cn = c + 1;
                union { u16x8 u; f16x8 f; } bn;
                bn.u = *(const u16x8*)(w3 + ((cn >> 1) * 64 + oc3) * 64 + (cn & 1) * 32 + q * 8);
                B3n = bn.f;
            }
            int kp = c >> 1, ky = kp / 3, kx = kp - ky * 3;
            int aoff = (ky * 10 + kx) * 64 + (c & 1) * 32;
            #pragma unroll
            for (int j = 0; j < 4; ++j) {
                union { u16x8 u; f16x8 f; } av;
                av.u = *(const u16x8*)(p2s + mbase[j] + aoff);
                acc3[j] = __builtin_amdgcn_mfma_f32_16x16x32_f16(av.f, B3c, acc3[j], 0, 0, 0);
            }
            B3c = B3n;
        }
        #pragma unroll
        for (int j = 0; j < 4; ++j)
        #pragma unroll
        for (int r = 0; r < 4; ++r) {
            int row = j * 16 + q * 4 + r;
            c3buf[row * 64 + oc3] = f2h(acc3[j][r]);   // pre-PReLU
        }
    }
    __syncthreads();

    // pool3 2x2 s2 (8->4), packed max + packed PReLU -> p3 [16][64]
    if (tid < 128) {
        int ocg = tid & 7, r = tid >> 3;   // r = output px 0..15
        int py = r >> 2, pxo = r & 3;
        f16x8 mx;
        #pragma unroll
        for (int j = 0; j < 8; ++j) mx[j] = (_Float16)(-60000.f);
        #pragma unroll
        for (int ky = 0; ky < 2; ++ky)
        #pragma unroll
        for (int kx = 0; kx < 2; ++kx) {
            union { uint4 u; f16x8 f; } d;
            d.u = *(const uint4*)&c3buf[((py * 2 + ky) * 8 + pxo * 2 + kx) * 64 + ocg * 8];
            mx = __builtin_elementwise_max(mx, d.f);
        }
        union { uint4 u; f16x8 f; } aal;
        aal.u = *(const uint4*)&a3h[ocg * 8];
        union { f16x8 f; uint4 u; } o; o.f = prelu8(mx, aal.f);
        *(uint4*)&p3[r * 64 + ocg * 8] = o.u;
    }
    __syncthreads();

    // conv4: wave w owns oc-tiles 2w,2w+1; 8 chunks; bias in init, scalar PReLU
    {
        int px = l16 < 9 ? l16 : 8;
        int oy = px / 3, ox = px - oy * 3;
        const int mb4 = (oy * 4 + ox) * 64 + q * 8;
        const int oc4a = (w * 2) * 16 + l16, oc4b = (w * 2 + 1) * 16 + l16;
        const float b4a = c4b[oc4a], b4b = c4b[oc4b];
        f32x4 acc4[2] = {{b4a, b4a, b4a, b4a}, {b4b, b4b, b4b, b4b}};
        f16x8 B4c[2];
        {
            union { u16x8 u; f16x8 f; } b0, b1;
            b0.u = *(const u16x8*)(w4 + oc4a * 64 + q * 8);
            b1.u = *(const u16x8*)(w4 + oc4b * 64 + q * 8);
            B4c[0] = b0.f; B4c[1] = b1.f;
        }
        for (int c = 0; c < 8; ++c) {
            f16x8 B4n[2] = {B4c[0], B4c[1]};
            if (c < 7) {
                int cn = c + 1;
                int boff = (cn >> 1) * 8192 + (cn & 1) * 32 + q * 8;
                union { u16x8 u; f16x8 f; } b0, b1;
                b0.u = *(const u16x8*)(w4 + boff + oc4a * 64);
                b1.u = *(const u16x8*)(w4 + boff + oc4b * 64);
                B4n[0] = b0.f; B4n[1] = b1.f;
            }
            int kp = c >> 1, ky = kp >> 1, kx = kp & 1;
            union { u16x8 u; f16x8 f; } av;
            av.u = *(const u16x8*)(p3 + mb4 + (ky * 4 + kx) * 64 + (c & 1) * 32);
            acc4[0] = __builtin_amdgcn_mfma_f32_16x16x32_f16(av.f, B4c[0], acc4[0], 0, 0, 0);
            acc4[1] = __builtin_amdgcn_mfma_f32_16x16x32_f16(av.f, B4c[1], acc4[1], 0, 0, 0);
            B4c[0] = B4n[0]; B4c[1] = B4n[1];
        }
        #pragma unroll
        for (int h = 0; h < 2; ++h) {
            int oc = h ? oc4b : oc4a;
            float al = a4[oc];
            #pragma unroll
            for (int r = 0; r < 4; ++r) {
                int row = q * 4 + r;
                if (row < 9) {
                    int hy = row / 3, wx = row - hy * 3;
                    float val = acc4[h][r];
                    val = fmaxf(val, 0.f) + al * fminf(val, 0.f);
                    flat[(unsigned)n * 1152u + (wx * 3 + hy) * 128 + oc] = f2h(val);
                }
            }
        }
    }
}

// ---------------------------------------------------------------------------
// K5 (R15, unchanged): merged d5 GEMM + heads; bias in acc-init.
// ---------------------------------------------------------------------------
__global__ __launch_bounds__(256, 2)
void k5_fused(const unsigned short* __restrict__ flat, const unsigned short* __restrict__ w5,
              const float* __restrict__ d5b, const float* __restrict__ a5,
              const float* __restrict__ d61w, const float* __restrict__ d61b,
              const float* __restrict__ d62w, const float* __restrict__ d62b,
              const float* __restrict__ d63w, const float* __restrict__ d63b,
              float* __restrict__ out) {
    __shared__ float hL[16 * 260];
    __shared__ float wl[16 * 260];
    __shared__ float lg[256];
    const int blk = blockIdx.x, tid = threadIdx.x;
    const int w = tid >> 6, lane = tid & 63, q = lane >> 4, l16 = lane & 15;
    const int img0 = blk * 16;
    const int img = img0 + l16;

    f32x4 acc[4];
    #pragma unroll
    for (int nt = 0; nt < 4; ++nt) {
        float b = d5b[w * 64 + nt * 16 + l16];
        acc[nt] = f32x4{b, b, b, b};
    }

    for (int c = 0; c < 36; ++c) {
        int k0 = c * 32 + q * 8;
        union { u16x8 u; f16x8 f; } av;
        av.u = *(const u16x8*)(flat + (unsigned)img * 1152u + k0);
        #pragma unroll
        for (int nt = 0; nt < 4; ++nt) {
            int oc = w * 64 + nt * 16 + l16;
            union { u16x8 u; f16x8 f; } bv;
            bv.u = *(const u16x8*)(w5 + (unsigned)oc * 1152u + k0);
            acc[nt] = __builtin_amdgcn_mfma_f32_16x16x32_f16(av.f, bv.f, acc[nt], 0, 0, 0);
        }
    }
    // epilogue: PReLU -> hL (fp32); C row=q*4+r=image, col=l16
    #pragma unroll
    for (int nt = 0; nt < 4; ++nt) {
        int oc = w * 64 + nt * 16 + l16;
        float al = a5[oc];
        #pragma unroll
        for (int r = 0; r < 4; ++r) {
            int im = q * 4 + r;
            float v = acc[nt][r];
            v = fmaxf(v, 0.f) + al * fminf(v, 0.f);
            hL[im * 260 + oc] = v;
        }
    }
    // stage 16 head weight rows (fp32)
    {
        int o = tid >> 4, seg = tid & 15;
        const float* wrow = (o < 2) ? d61w + o * 256
                          : (o < 6) ? d62w + (o - 2) * 256
                          :           d63w + (o - 6) * 256;
        #pragma unroll
        for (int j = 0; j < 4; ++j)
            *(float4*)&wl[o * 260 + seg * 16 + j * 4] = ((const float4*)wrow)[seg * 4 + j];
    }
    __syncthreads();

    const int im = tid >> 4, o = tid & 15;
    {
        float bias = (o < 2) ? d61b[o] : (o < 6) ? d62b[o - 2] : d63b[o - 6];
        float s = bias;
        const float4* ha = (const float4*)&hL[im * 260];
        const float4* wa = (const float4*)&wl[o * 260];
        #pragma unroll 8
        for (int k = 0; k < 64; ++k) {
            float4 a = ha[k], b = wa[k];
            s += a.x * b.x + a.y * b.y + a.z * b.z + a.w * b.w;
        }
        lg[im * 16 + o] = s;
    }
    __syncthreads();
    {
        int gimg = img0 + im;
        float v = lg[im * 16 + o];
        if (o >= 2 && o < 6) {
            out[gimg * 4 + (o - 2)] = v;                       // b [N,4]
        } else if (o >= 6) {
            out[8192 + gimg * 10 + (o - 6)] = v;               // c [N,10]
        } else {
            float l0 = lg[im * 16 + 0], l1 = lg[im * 16 + 1];
            float mx = fmaxf(l0, l1);
            float e0 = __expf(l0 - mx), e1 = __expf(l1 - mx);
            out[28672 + gimg * 2 + o] = (o == 0 ? e0 : e1) / (e0 + e1);   // a [N,2]
        }
    }
}

// ---------------------------------------------------------------------------
extern "C" void kernel_launch(void* const* d_in, const int* in_sizes, int n_in,
                              void* d_out, int out_size, void* d_ws, size_t ws_size,
                              hipStream_t stream) {
    (void)in_sizes; (void)n_in; (void)out_size; (void)ws_size;
    const float* x    = (const float*)d_in[0];
    const float* c1w  = (const float*)d_in[1];
    const float* c1b  = (const float*)d_in[2];
    const float* a1   = (const float*)d_in[3];
    const float* c2w  = (const float*)d_in[4];
    const float* c2b  = (const float*)d_in[5];
    const float* a2   = (const float*)d_in[6];
    const float* c3w  = (const float*)d_in[7];
    const float* c3b  = (const float*)d_in[8];
    const float* a3   = (const float*)d_in[9];
    const float* c4w  = (const float*)d_in[10];
    const float* c4b  = (const float*)d_in[11];
    const float* a4   = (const float*)d_in[12];
    const float* d5w  = (const float*)d_in[13];
    const float* d5b  = (const float*)d_in[14];
    const float* a5   = (const float*)d_in[15];
    const float* d61w = (const float*)d_in[16];
    const float* d61b = (const float*)d_in[17];
    const float* d62w = (const float*)d_in[18];
    const float* d62b = (const float*)d_in[19];
    const float* d63w = (const float*)d_in[20];
    const float* d63b = (const float*)d_in[21];

    char* ws = (char*)d_ws;
    // region plan:
    //   p1    @ 0          : 69,337,088 B  (live through k23_fused)
    //   flat  @ 69,337,088 : 4,718,592 B
    //   weights @ 186,777,600 : ~766 KB
    unsigned short* p1    = (unsigned short*)(ws + 0);
    unsigned short* flat  = (unsigned short*)(ws + 69337088);
    unsigned short* w2    = (unsigned short*)(ws + 186777600);
    unsigned short* w3    = (unsigned short*)(ws + 186814464);
    unsigned short* w4    = (unsigned short*)(ws + 186888192);
    unsigned short* w5    = (unsigned short*)(ws + 186953728);

    k1_conv1 <<<2122, 256, 0, stream>>>(x, c1w, c1b, a1, p1,
                                        c2w, c3w, c4w, d5w, w2, w3, w4, w5);
    k23_fused<<<2048, 256, 0, stream>>>(p1, w2, c2b, a2, w3, c3b, a3, w4, c4b, a4, flat);
    k5_fused <<<128, 256, 0, stream>>>(flat, w5, d5b, a5, d61w, d61b, d62w, d62b,
                                       d63w, d63b, (float*)d_out);
}